// Round 1
// baseline (137.267 us; speedup 1.0000x reference)
//
#include <hip/hip_runtime.h>
#include <hip/hip_bf16.h>

// OuterAttention: A=B=8192, E1=E2=C=M=1024.
// Key algebraic reduction: matrix_ab is only used via row/col sums:
//   logits_a = p1 @ (sum_b p2[b,:]),  logits_b = p2 @ (sum_a p1[a,:])
// -> never materialize the 8192x8192 matrix.

#define A_ROWS 8192
#define EDIM   1024
#define MDIM   1024
#define KDIM   1024

typedef __attribute__((ext_vector_type(8))) short bf16x8;
typedef __attribute__((ext_vector_type(4))) float f32x4;

// ---- workspace layout (bytes). Total required: 104,939,520 B (~100.1 MB) ----
#define OFF_BIAS1   0ull
#define OFF_BIAS2   4096ull
#define OFF_S1      8192ull
#define OFF_S2      12288ull
#define OFF_LOGA    16384ull          // 8192 floats
#define OFF_LOGB    49152ull          // 8192 floats (must be LOGA + 32768)
#define OFF_P1      81920ull          // 8192*1024 f32 = 32 MB
#define OFF_P2      (OFF_P1 + 33554432ull)
#define OFF_SEQ1B   (OFF_P2 + 33554432ull)   // 8192*1024 bf16 = 16 MB
#define OFF_SEQ2B   (OFF_SEQ1B + 16777216ull)
#define OFF_W1B     (OFF_SEQ2B + 16777216ull) // 1024*1024 bf16 = 2 MB
#define OFF_W2B     (OFF_W1B + 2097152ull)

__device__ __forceinline__ ushort f2bf(float x) {
  union { float f; unsigned u; } v; v.f = x;
  unsigned r = v.u + 0x7fffu + ((v.u >> 16) & 1u);   // RNE to bf16
  return (ushort)(r >> 16);
}

// ---- f32 -> bf16 convert (vectorized float4 -> ushort4) ----
__global__ __launch_bounds__(256) void cvt_bf16(const float* __restrict__ in,
                                                ushort* __restrict__ out, int n4) {
  int stride = gridDim.x * blockDim.x;
  for (int i = blockIdx.x * blockDim.x + threadIdx.x; i < n4; i += stride) {
    float4 f = reinterpret_cast<const float4*>(in)[i];
    ushort4 o;
    o.x = f2bf(f.x); o.y = f2bf(f.y); o.z = f2bf(f.z); o.w = f2bf(f.w);
    reinterpret_cast<ushort4*>(out)[i] = o;
  }
}

// ---- bias[m] = (W_ctx @ context)[m] + b[m] ; one wave per m ----
__global__ __launch_bounds__(256) void ctx_bias_k(const float* __restrict__ W,
    const float* __restrict__ c, const float* __restrict__ b, float* __restrict__ bias) {
  int wave = threadIdx.x >> 6, lane = threadIdx.x & 63;
  int m = blockIdx.x * 4 + wave;
  const float4* wr = reinterpret_cast<const float4*>(W + (size_t)m * KDIM);
  const float4* cv = reinterpret_cast<const float4*>(c);
  float acc = 0.f;
#pragma unroll
  for (int ch = 0; ch < 4; ++ch) {
    float4 a = wr[ch * 64 + lane], d = cv[ch * 64 + lane];
    acc += a.x * d.x + a.y * d.y + a.z * d.z + a.w * d.w;
  }
  for (int o = 32; o; o >>= 1) acc += __shfl_down(acc, o);
  if (lane == 0) bias[m] = acc + b[m];
}

// ---- fused GEMM: P = elu(Ab @ Bb^T + bias), S[col] += column sums ----
// Ab: [Mrows][K] bf16 row-major (seq), Bb: [Ncols][K] bf16 row-major (W).
// m97 structure: 128x128 tile, BK=32, 4 waves (2x2), each wave 64x64 out,
// global_load_lds width-16 staging, double-buffered LDS, 1 barrier/iter.
__global__ __launch_bounds__(256) void gemm_fused(
    const ushort* __restrict__ Ab, const ushort* __restrict__ Bb,
    const float* __restrict__ bias, float* __restrict__ P, float* __restrict__ S,
    int Ncols, int K) {
  __shared__ __align__(16) ushort ldsA[2][128 * 32];
  __shared__ __align__(16) ushort ldsB[2][128 * 32];
  const int tid = threadIdx.x;
  const int lane = tid & 63;
  const int wave = tid >> 6;
  const int brow = blockIdx.x * 128, bcol = blockIdx.y * 128;
  const int wr = (wave >> 1) * 64, wc = (wave & 1) * 64;
  const int r = lane & 15, kq = lane >> 4;

  f32x4 acc[4][4] = {};

  // stage one 128x32 A-tile + B-tile into lds buf (each 8 KB, 2 issues/thread)
  auto stage = [&](int buf, int k0) {
#pragma unroll
    for (int i = 0; i < 2; ++i) {
      int c = i * 256 + tid;                      // 16B chunk id; 4 chunks/row
      const char* ga = (const char*)Ab +
          (((size_t)(brow + (c >> 2)) * K + k0) * 2 + (size_t)(c & 3) * 16);
      const char* gb = (const char*)Bb +
          (((size_t)(bcol + (c >> 2)) * K + k0) * 2 + (size_t)(c & 3) * 16);
      __builtin_amdgcn_global_load_lds(
          (const __attribute__((address_space(1))) void*)ga,
          (__attribute__((address_space(3))) void*)((char*)&ldsA[buf][0] + (size_t)c * 16),
          16, 0, 0);
      __builtin_amdgcn_global_load_lds(
          (const __attribute__((address_space(1))) void*)gb,
          (__attribute__((address_space(3))) void*)((char*)&ldsB[buf][0] + (size_t)c * 16),
          16, 0, 0);
    }
  };

  stage(0, 0);
  const int NK = K / 32;
  for (int kt = 0; kt < NK; ++kt) {
    __syncthreads();                      // compiler drains vmcnt+lgkm before barrier
    if (kt + 1 < NK) stage((kt + 1) & 1, (kt + 1) * 32);
    const ushort* la = &ldsA[kt & 1][0];
    const ushort* lb = &ldsB[kt & 1][0];
    bf16x8 af[4], bfv[4];
#pragma unroll
    for (int mf = 0; mf < 4; ++mf)
      af[mf] = *reinterpret_cast<const bf16x8*>(la + (wr + mf * 16 + r) * 32 + kq * 8);
#pragma unroll
    for (int nf = 0; nf < 4; ++nf)
      bfv[nf] = *reinterpret_cast<const bf16x8*>(lb + (wc + nf * 16 + r) * 32 + kq * 8);
#pragma unroll
    for (int mf = 0; mf < 4; ++mf)
#pragma unroll
      for (int nf = 0; nf < 4; ++nf)
        acc[mf][nf] = __builtin_amdgcn_mfma_f32_16x16x32_bf16(af[mf], bfv[nf], acc[mf][nf], 0, 0, 0);
  }

  // epilogue: bias + ELU, store P (f32), fused per-column partial sums -> S
#pragma unroll
  for (int nf = 0; nf < 4; ++nf) {
    int col = bcol + wc + nf * 16 + r;
    float bv = bias[col];
    float cs = 0.f;
#pragma unroll
    for (int mf = 0; mf < 4; ++mf) {
#pragma unroll
      for (int j = 0; j < 4; ++j) {
        int row = brow + wr + mf * 16 + kq * 4 + j;   // C/D: col=lane&15, row=(lane>>4)*4+j
        float v = acc[mf][nf][j] + bv;
        v = v > 0.f ? v : expm1f(v);
        P[(size_t)row * Ncols + col] = v;
        cs += v;
      }
    }
    cs += __shfl_xor(cs, 16);
    cs += __shfl_xor(cs, 32);
    if (kq == 0) atomicAdd(&S[col], cs);
  }
}

// ---- logits[row] = dot(P[row,:], s) ; one wave per row ----
__global__ __launch_bounds__(256) void gemv_logits_k(const float* __restrict__ P,
    const float* __restrict__ s, float* __restrict__ L) {
  int wave = threadIdx.x >> 6, lane = threadIdx.x & 63;
  int row = blockIdx.x * 4 + wave;
  const float4* pr = reinterpret_cast<const float4*>(P + (size_t)row * MDIM);
  const float4* sv = reinterpret_cast<const float4*>(s);
  float acc = 0.f;
#pragma unroll
  for (int ch = 0; ch < 4; ++ch) {
    float4 a = pr[ch * 64 + lane], d = sv[ch * 64 + lane];
    acc += a.x * d.x + a.y * d.y + a.z * d.z + a.w * d.w;
  }
  for (int o = 32; o; o >>= 1) acc += __shfl_down(acc, o);
  if (lane == 0) L[row] = acc;
}

// ---- in-place softmax over 8192 logits; blockIdx.x selects a/b buffer ----
__global__ __launch_bounds__(256) void softmax_k(float* __restrict__ Lbase) {
  float* L = Lbase + (size_t)blockIdx.x * 8192;
  __shared__ float red[256];
  int tid = threadIdx.x;
  float v[32];
  float m = -3.4e38f;
#pragma unroll
  for (int k = 0; k < 32; ++k) { v[k] = L[tid + k * 256]; m = fmaxf(m, v[k]); }
  red[tid] = m; __syncthreads();
  for (int o = 128; o; o >>= 1) {
    if (tid < o) red[tid] = fmaxf(red[tid], red[tid + o]);
    __syncthreads();
  }
  m = red[0]; __syncthreads();
  float sum = 0.f;
#pragma unroll
  for (int k = 0; k < 32; ++k) { v[k] = expf(v[k] - m); sum += v[k]; }
  red[tid] = sum; __syncthreads();
  for (int o = 128; o; o >>= 1) {
    if (tid < o) red[tid] += red[tid + o];
    __syncthreads();
  }
  float inv = 1.f / red[0];
#pragma unroll
  for (int k = 0; k < 32; ++k) L[tid + k * 256] = v[k] * inv;
}

// ---- att[e] = sum_a w[a] * seq[a,e] ; partial chunks + atomicAdd ----
__global__ __launch_bounds__(256) void att_k(const float* __restrict__ seq1,
    const float* __restrict__ seq2, const float* __restrict__ wa,
    const float* __restrict__ wb, float* __restrict__ out) {
  int z = blockIdx.z;
  const float* seq = z ? seq2 : seq1;
  const float* w = z ? wb : wa;
  float* o = out + (size_t)z * EDIM;
  int e = blockIdx.x * 256 + threadIdx.x;
  int a0 = blockIdx.y * 512;
  float acc = 0.f;
  for (int a = a0; a < a0 + 512; ++a)
    acc += w[a] * seq[(size_t)a * EDIM + e];
  atomicAdd(&o[e], acc);
}

extern "C" void kernel_launch(void* const* d_in, const int* in_sizes, int n_in,
                              void* d_out, int out_size, void* d_ws, size_t ws_size,
                              hipStream_t stream) {
  const float* seq1 = (const float*)d_in[0];
  const float* seq2 = (const float*)d_in[1];
  const float* ctx  = (const float*)d_in[2];
  const float* Wc1  = (const float*)d_in[3];
  const float* Wc2  = (const float*)d_in[4];
  const float* W1   = (const float*)d_in[5];
  const float* b1   = (const float*)d_in[6];
  const float* W2   = (const float*)d_in[7];
  const float* b2   = (const float*)d_in[8];
  float* out = (float*)d_out;
  char* ws = (char*)d_ws;

  float* bias1 = (float*)(ws + OFF_BIAS1);
  float* bias2 = (float*)(ws + OFF_BIAS2);
  float* s1    = (float*)(ws + OFF_S1);
  float* s2    = (float*)(ws + OFF_S2);
  float* loga  = (float*)(ws + OFF_LOGA);
  float* p1    = (float*)(ws + OFF_P1);
  float* p2    = (float*)(ws + OFF_P2);
  ushort* seq1b = (ushort*)(ws + OFF_SEQ1B);
  ushort* seq2b = (ushort*)(ws + OFF_SEQ2B);
  ushort* w1b   = (ushort*)(ws + OFF_W1B);
  ushort* w2b   = (ushort*)(ws + OFF_W2B);

  // zero atomic accumulation targets (harness does not re-poison between replays)
  hipMemsetAsync(d_out, 0, sizeof(float) * 2048, stream);
  hipMemsetAsync(ws + OFF_S1, 0, 8192, stream);   // s1 + s2

  ctx_bias_k<<<256, 256, 0, stream>>>(Wc1, ctx, b1, bias1);
  ctx_bias_k<<<256, 256, 0, stream>>>(Wc2, ctx, b2, bias2);

  cvt_bf16<<<2048, 256, 0, stream>>>(seq1, seq1b, A_ROWS * EDIM / 4);
  cvt_bf16<<<2048, 256, 0, stream>>>(seq2, seq2b, A_ROWS * EDIM / 4);
  cvt_bf16<<<1024, 256, 0, stream>>>(W1, w1b, MDIM * EDIM / 4);
  cvt_bf16<<<1024, 256, 0, stream>>>(W2, w2b, MDIM * EDIM / 4);

  dim3 gg(A_ROWS / 128, MDIM / 128);
  gemm_fused<<<gg, 256, 0, stream>>>(seq1b, w1b, bias1, p1, s1, MDIM, EDIM);
  gemm_fused<<<gg, 256, 0, stream>>>(seq2b, w2b, bias2, p2, s2, MDIM, EDIM);

  gemv_logits_k<<<2048, 256, 0, stream>>>(p1, s2, loga);
  gemv_logits_k<<<2048, 256, 0, stream>>>(p2, s1, loga + 8192);

  softmax_k<<<2, 256, 0, stream>>>(loga);

  att_k<<<dim3(4, 16, 2), 256, 0, stream>>>(seq1, seq2, loga, loga + 8192, out);
}

// Round 2
// 126.360 us; speedup vs baseline: 1.0863x; 1.0863x over previous
//
#include <hip/hip_runtime.h>
#include <hip/hip_bf16.h>

// OuterAttention: A=B=8192, E1=E2=C=M=1024.
// matrix_ab only used via row/col sums -> logits_a = p1 @ sum(p2), logits_b = p2 @ sum(p1).
// Round 2: z-merged GEMM (4 blocks/CU), bf16 P, bf16 att reads, merged small kernels.

#define A_ROWS 8192
#define EDIM   1024
#define MDIM   1024
#define KGEMM  1024

typedef __attribute__((ext_vector_type(8))) short bf16x8;
typedef __attribute__((ext_vector_type(4))) short bf16x4;
typedef __attribute__((ext_vector_type(4))) float f32x4;

// ---- workspace layout (bytes). Total ~68.2 MB ----
#define OFF_BIAS1   0ull
#define OFF_BIAS2   4096ull
#define OFF_S1      8192ull
#define OFF_S2      12288ull
#define OFF_LOGA    16384ull                  // 2 x 8192 floats
#define OFF_P1      81920ull                  // 8192*1024 bf16 = 16 MB
#define OFF_P2      (OFF_P1 + 16777216ull)
#define OFF_SEQ1B   (OFF_P2 + 16777216ull)    // 16 MB
#define OFF_SEQ2B   (OFF_SEQ1B + 16777216ull)
#define OFF_W1B     (OFF_SEQ2B + 16777216ull) // 2 MB
#define OFF_W2B     (OFF_W1B + 2097152ull)

__device__ __forceinline__ ushort f2bf(float x) {
  union { float f; unsigned u; } v; v.f = x;
  unsigned r = v.u + 0x7fffu + ((v.u >> 16) & 1u);   // RNE
  return (ushort)(r >> 16);
}
__device__ __forceinline__ float bf2f(ushort u) {
  union { unsigned u; float f; } v; v.u = (unsigned)u << 16; return v.f;
}

// ---- f32 -> bf16 convert, z picks array pair ----
__global__ __launch_bounds__(256) void cvt_pair(const float* __restrict__ in0,
    const float* __restrict__ in1, ushort* __restrict__ out0,
    ushort* __restrict__ out1, int n4) {
  const float* in = blockIdx.z ? in1 : in0;
  ushort* out = blockIdx.z ? out1 : out0;
  int stride = gridDim.x * blockDim.x;
  for (int i = blockIdx.x * blockDim.x + threadIdx.x; i < n4; i += stride) {
    float4 f = reinterpret_cast<const float4*>(in)[i];
    ushort4 o;
    o.x = f2bf(f.x); o.y = f2bf(f.y); o.z = f2bf(f.z); o.w = f2bf(f.w);
    reinterpret_cast<ushort4*>(out)[i] = o;
  }
}

// ---- bias[m] = (W_ctx @ context)[m] + b[m]; also zeros S ----
__global__ __launch_bounds__(256) void ctx_bias_k(
    const float* __restrict__ Wc1, const float* __restrict__ Wc2,
    const float* __restrict__ c, const float* __restrict__ b1,
    const float* __restrict__ b2, float* __restrict__ bias1,
    float* __restrict__ bias2, float* __restrict__ S1, float* __restrict__ S2) {
  int z = blockIdx.z;
  const float* W = z ? Wc2 : Wc1;
  const float* b = z ? b2 : b1;
  float* bias = z ? bias2 : bias1;
  float* S = z ? S2 : S1;
  int wave = threadIdx.x >> 6, lane = threadIdx.x & 63;
  int m = blockIdx.x * 4 + wave;
  const float4* wr = reinterpret_cast<const float4*>(W + (size_t)m * EDIM);
  const float4* cv = reinterpret_cast<const float4*>(c);
  float acc = 0.f;
#pragma unroll
  for (int ch = 0; ch < 4; ++ch) {
    float4 a = wr[ch * 64 + lane], d = cv[ch * 64 + lane];
    acc += a.x * d.x + a.y * d.y + a.z * d.z + a.w * d.w;
  }
  for (int o = 32; o; o >>= 1) acc += __shfl_down(acc, o);
  if (lane == 0) { bias[m] = acc + b[m]; S[m] = 0.f; }
}

// ---- fused GEMM: P = elu(Ab @ Bb^T + bias) [bf16], S[col] += col sums ----
// 128x128 tile, BK=32, 4 waves (2x2), 64x64 per wave, global_load_lds w=16,
// double-buffered LDS, z selects problem (1024 blocks total = 4 blocks/CU).
__global__ __launch_bounds__(256) void gemm_fused(
    const ushort* __restrict__ A1, const ushort* __restrict__ A2,
    const ushort* __restrict__ B1, const ushort* __restrict__ B2,
    const float* __restrict__ bias1, const float* __restrict__ bias2,
    ushort* __restrict__ P1, ushort* __restrict__ P2,
    float* __restrict__ S1, float* __restrict__ S2) {
  const int z = blockIdx.z;
  const ushort* __restrict__ Ab = z ? A2 : A1;
  const ushort* __restrict__ Bb = z ? B2 : B1;
  const float* __restrict__ bias = z ? bias2 : bias1;
  ushort* __restrict__ P = z ? P2 : P1;
  float* __restrict__ S = z ? S2 : S1;

  __shared__ __align__(16) ushort ldsA[2][128 * 32];
  __shared__ __align__(16) ushort ldsB[2][128 * 32];
  const int tid = threadIdx.x;
  const int lane = tid & 63;
  const int wave = tid >> 6;
  const int brow = blockIdx.x * 128, bcol = blockIdx.y * 128;
  const int wr = (wave >> 1) * 64, wc = (wave & 1) * 64;
  const int r = lane & 15, kq = lane >> 4;

  f32x4 acc[4][4] = {};

  auto stage = [&](int buf, int k0) {
#pragma unroll
    for (int i = 0; i < 2; ++i) {
      int c = i * 256 + tid;                      // 16B chunk id; 4 chunks/row
      const char* ga = (const char*)Ab +
          (((size_t)(brow + (c >> 2)) * KGEMM + k0) * 2 + (size_t)(c & 3) * 16);
      const char* gb = (const char*)Bb +
          (((size_t)(bcol + (c >> 2)) * KGEMM + k0) * 2 + (size_t)(c & 3) * 16);
      __builtin_amdgcn_global_load_lds(
          (const __attribute__((address_space(1))) void*)ga,
          (__attribute__((address_space(3))) void*)((char*)&ldsA[buf][0] + (size_t)c * 16),
          16, 0, 0);
      __builtin_amdgcn_global_load_lds(
          (const __attribute__((address_space(1))) void*)gb,
          (__attribute__((address_space(3))) void*)((char*)&ldsB[buf][0] + (size_t)c * 16),
          16, 0, 0);
    }
  };

  stage(0, 0);
  const int NK = KGEMM / 32;
  for (int kt = 0; kt < NK; ++kt) {
    __syncthreads();
    if (kt + 1 < NK) stage((kt + 1) & 1, (kt + 1) * 32);
    const ushort* la = &ldsA[kt & 1][0];
    const ushort* lb = &ldsB[kt & 1][0];
    bf16x8 af[4], bfv[4];
#pragma unroll
    for (int mf = 0; mf < 4; ++mf)
      af[mf] = *reinterpret_cast<const bf16x8*>(la + (wr + mf * 16 + r) * 32 + kq * 8);
#pragma unroll
    for (int nf = 0; nf < 4; ++nf)
      bfv[nf] = *reinterpret_cast<const bf16x8*>(lb + (wc + nf * 16 + r) * 32 + kq * 8);
#pragma unroll
    for (int mf = 0; mf < 4; ++mf)
#pragma unroll
      for (int nf = 0; nf < 4; ++nf)
        acc[mf][nf] = __builtin_amdgcn_mfma_f32_16x16x32_bf16(af[mf], bfv[nf], acc[mf][nf], 0, 0, 0);
  }

  // epilogue: bias + ELU, store P (bf16), fused per-column partial sums -> S
#pragma unroll
  for (int nf = 0; nf < 4; ++nf) {
    int col = bcol + wc + nf * 16 + r;
    float bv = bias[col];
    float cs = 0.f;
#pragma unroll
    for (int mf = 0; mf < 4; ++mf) {
#pragma unroll
      for (int j = 0; j < 4; ++j) {
        int row = brow + wr + mf * 16 + kq * 4 + j;   // C/D: col=lane&15, row=(lane>>4)*4+j
        float v = acc[mf][nf][j] + bv;
        v = v > 0.f ? v : expm1f(v);
        P[(size_t)row * MDIM + col] = f2bf(v);
        cs += v;
      }
    }
    cs += __shfl_xor(cs, 16);
    cs += __shfl_xor(cs, 32);
    if (kq == 0) atomicAdd(&S[col], cs);
  }
}

// ---- logits[row] = dot(P[row,:], s); one wave per row; z merges a/b ----
__global__ __launch_bounds__(256) void gemv_logits_k(
    const ushort* __restrict__ P1, const ushort* __restrict__ P2,
    const float* __restrict__ S1, const float* __restrict__ S2,
    float* __restrict__ L) {
  int z = blockIdx.z;
  const ushort* P = z ? P2 : P1;
  const float* s = z ? S1 : S2;   // logits_a uses s2, logits_b uses s1
  float* Lz = L + (size_t)z * 8192;
  int wave = threadIdx.x >> 6, lane = threadIdx.x & 63;
  int row = blockIdx.x * 4 + wave;
  const ushort* pr = P + (size_t)row * MDIM;
  float acc = 0.f;
#pragma unroll
  for (int ch = 0; ch < 2; ++ch) {
    int base = ch * 512 + lane * 8;
    bf16x8 pv = *reinterpret_cast<const bf16x8*>(pr + base);
    const float4* sv = reinterpret_cast<const float4*>(s + base);
    float4 sa = sv[0], sb = sv[1];
    acc += bf2f((ushort)pv[0]) * sa.x + bf2f((ushort)pv[1]) * sa.y +
           bf2f((ushort)pv[2]) * sa.z + bf2f((ushort)pv[3]) * sa.w +
           bf2f((ushort)pv[4]) * sb.x + bf2f((ushort)pv[5]) * sb.y +
           bf2f((ushort)pv[6]) * sb.z + bf2f((ushort)pv[7]) * sb.w;
  }
  for (int o = 32; o; o >>= 1) acc += __shfl_down(acc, o);
  if (lane == 0) Lz[row] = acc;
}

// ---- in-place softmax over 8192 logits; blockIdx.x selects a/b ----
__global__ __launch_bounds__(256) void softmax_k(float* __restrict__ Lbase) {
  float* L = Lbase + (size_t)blockIdx.x * 8192;
  __shared__ float red[256];
  int tid = threadIdx.x;
  float v[32];
  float m = -3.4e38f;
#pragma unroll
  for (int k = 0; k < 32; ++k) { v[k] = L[tid + k * 256]; m = fmaxf(m, v[k]); }
  red[tid] = m; __syncthreads();
  for (int o = 128; o; o >>= 1) {
    if (tid < o) red[tid] = fmaxf(red[tid], red[tid + o]);
    __syncthreads();
  }
  m = red[0]; __syncthreads();
  float sum = 0.f;
#pragma unroll
  for (int k = 0; k < 32; ++k) { v[k] = expf(v[k] - m); sum += v[k]; }
  red[tid] = sum; __syncthreads();
  for (int o = 128; o; o >>= 1) {
    if (tid < o) red[tid] += red[tid + o];
    __syncthreads();
  }
  float inv = 1.f / red[0];
#pragma unroll
  for (int k = 0; k < 32; ++k) L[tid + k * 256] = v[k] * inv;
}

// ---- att[e] = sum_a w[a] * seq_bf16[a,e]; y partitions rows, atomicAdd ----
__global__ __launch_bounds__(256) void att_k(const ushort* __restrict__ s1b,
    const ushort* __restrict__ s2b, const float* __restrict__ wv,
    float* __restrict__ out) {
  int z = blockIdx.z;
  const ushort* seq = z ? s2b : s1b;
  const float* w = wv + (size_t)z * 8192;
  float* o = out + (size_t)z * EDIM;
  int e4 = threadIdx.x;                 // owns cols e4*4 .. e4*4+3
  int a0 = blockIdx.y * 256;
  float a0c = 0.f, a1c = 0.f, a2c = 0.f, a3c = 0.f;
  for (int a = a0; a < a0 + 256; ++a) {
    float wa = w[a];
    bf16x4 v = *reinterpret_cast<const bf16x4*>(seq + (size_t)a * EDIM + e4 * 4);
    a0c += wa * bf2f((ushort)v[0]);
    a1c += wa * bf2f((ushort)v[1]);
    a2c += wa * bf2f((ushort)v[2]);
    a3c += wa * bf2f((ushort)v[3]);
  }
  atomicAdd(&o[e4 * 4 + 0], a0c);
  atomicAdd(&o[e4 * 4 + 1], a1c);
  atomicAdd(&o[e4 * 4 + 2], a2c);
  atomicAdd(&o[e4 * 4 + 3], a3c);
}

extern "C" void kernel_launch(void* const* d_in, const int* in_sizes, int n_in,
                              void* d_out, int out_size, void* d_ws, size_t ws_size,
                              hipStream_t stream) {
  const float* seq1 = (const float*)d_in[0];
  const float* seq2 = (const float*)d_in[1];
  const float* ctx  = (const float*)d_in[2];
  const float* Wc1  = (const float*)d_in[3];
  const float* Wc2  = (const float*)d_in[4];
  const float* W1   = (const float*)d_in[5];
  const float* b1   = (const float*)d_in[6];
  const float* W2   = (const float*)d_in[7];
  const float* b2   = (const float*)d_in[8];
  float* out = (float*)d_out;
  char* ws = (char*)d_ws;

  float* bias1 = (float*)(ws + OFF_BIAS1);
  float* bias2 = (float*)(ws + OFF_BIAS2);
  float* s1    = (float*)(ws + OFF_S1);
  float* s2    = (float*)(ws + OFF_S2);
  float* loga  = (float*)(ws + OFF_LOGA);
  ushort* p1   = (ushort*)(ws + OFF_P1);
  ushort* p2   = (ushort*)(ws + OFF_P2);
  ushort* seq1b = (ushort*)(ws + OFF_SEQ1B);
  ushort* seq2b = (ushort*)(ws + OFF_SEQ2B);
  ushort* w1b   = (ushort*)(ws + OFF_W1B);
  ushort* w2b   = (ushort*)(ws + OFF_W2B);

  // zero atomic accumulation target (harness poisons once, never re-poisons)
  hipMemsetAsync(d_out, 0, sizeof(float) * 2048, stream);

  ctx_bias_k<<<dim3(256, 1, 2), 256, 0, stream>>>(Wc1, Wc2, ctx, b1, b2,
                                                  bias1, bias2, s1, s2);
  cvt_pair<<<dim3(1024, 1, 2), 256, 0, stream>>>(seq1, seq2, seq1b, seq2b,
                                                 A_ROWS * EDIM / 4);
  cvt_pair<<<dim3(128, 1, 2), 256, 0, stream>>>(W1, W2, w1b, w2b,
                                                MDIM * EDIM / 4);

  gemm_fused<<<dim3(A_ROWS / 128, MDIM / 128, 2), 256, 0, stream>>>(
      seq1b, seq2b, w1b, w2b, bias1, bias2, p1, p2, s1, s2);

  gemv_logits_k<<<dim3(2048, 1, 2), 256, 0, stream>>>(p1, p2, s1, s2, loga);

  softmax_k<<<2, 256, 0, stream>>>(loga);

  att_k<<<dim3(1, 32, 2), 256, 0, stream>>>(seq1b, seq2b, loga, out);
}

// Round 3
// 123.045 us; speedup vs baseline: 1.1156x; 1.0269x over previous
//
#include <hip/hip_runtime.h>
#include <hip/hip_bf16.h>

// OuterAttention: A=B=8192, E1=E2=C=M=1024.
// matrix_ab only used via row/col sums -> logits_a = p1 @ sum(p2), logits_b = p2 @ sum(p1).
// Round 3: hoisted/incremental addressing in GEMM K-loop (VALU was 43%),
// fast ELU epilogue, att_k at 1 block/CU.

#define A_ROWS 8192
#define EDIM   1024
#define MDIM   1024
#define KGEMM  1024

typedef __attribute__((ext_vector_type(8))) short bf16x8;
typedef __attribute__((ext_vector_type(4))) short bf16x4;
typedef __attribute__((ext_vector_type(4))) float f32x4;

// ---- workspace layout (bytes). Total ~68.2 MB ----
#define OFF_BIAS1   0ull
#define OFF_BIAS2   4096ull
#define OFF_S1      8192ull
#define OFF_S2      12288ull
#define OFF_LOGA    16384ull                  // 2 x 8192 floats
#define OFF_P1      81920ull                  // 8192*1024 bf16 = 16 MB
#define OFF_P2      (OFF_P1 + 16777216ull)
#define OFF_SEQ1B   (OFF_P2 + 16777216ull)    // 16 MB
#define OFF_SEQ2B   (OFF_SEQ1B + 16777216ull)
#define OFF_W1B     (OFF_SEQ2B + 16777216ull) // 2 MB
#define OFF_W2B     (OFF_W1B + 2097152ull)

__device__ __forceinline__ ushort f2bf(float x) {
  union { float f; unsigned u; } v; v.f = x;
  unsigned r = v.u + 0x7fffu + ((v.u >> 16) & 1u);   // RNE
  return (ushort)(r >> 16);
}
__device__ __forceinline__ float bf2f(ushort u) {
  union { unsigned u; float f; } v; v.u = (unsigned)u << 16; return v.f;
}

#define GLOAD16(src, dst) __builtin_amdgcn_global_load_lds( \
    (const __attribute__((address_space(1))) void*)(src),   \
    (__attribute__((address_space(3))) void*)(dst), 16, 0, 0)

// ---- f32 -> bf16 convert, z picks array pair ----
__global__ __launch_bounds__(256) void cvt_pair(const float* __restrict__ in0,
    const float* __restrict__ in1, ushort* __restrict__ out0,
    ushort* __restrict__ out1, int n4) {
  const float* in = blockIdx.z ? in1 : in0;
  ushort* out = blockIdx.z ? out1 : out0;
  int stride = gridDim.x * blockDim.x;
  for (int i = blockIdx.x * blockDim.x + threadIdx.x; i < n4; i += stride) {
    float4 f = reinterpret_cast<const float4*>(in)[i];
    ushort4 o;
    o.x = f2bf(f.x); o.y = f2bf(f.y); o.z = f2bf(f.z); o.w = f2bf(f.w);
    reinterpret_cast<ushort4*>(out)[i] = o;
  }
}

// ---- bias[m] = (W_ctx @ context)[m] + b[m]; also zeros S ----
__global__ __launch_bounds__(256) void ctx_bias_k(
    const float* __restrict__ Wc1, const float* __restrict__ Wc2,
    const float* __restrict__ c, const float* __restrict__ b1,
    const float* __restrict__ b2, float* __restrict__ bias1,
    float* __restrict__ bias2, float* __restrict__ S1, float* __restrict__ S2) {
  int z = blockIdx.z;
  const float* W = z ? Wc2 : Wc1;
  const float* b = z ? b2 : b1;
  float* bias = z ? bias2 : bias1;
  float* S = z ? S2 : S1;
  int wave = threadIdx.x >> 6, lane = threadIdx.x & 63;
  int m = blockIdx.x * 4 + wave;
  const float4* wr = reinterpret_cast<const float4*>(W + (size_t)m * EDIM);
  const float4* cv = reinterpret_cast<const float4*>(c);
  float acc = 0.f;
#pragma unroll
  for (int ch = 0; ch < 4; ++ch) {
    float4 a = wr[ch * 64 + lane], d = cv[ch * 64 + lane];
    acc += a.x * d.x + a.y * d.y + a.z * d.z + a.w * d.w;
  }
  for (int o = 32; o; o >>= 1) acc += __shfl_down(acc, o);
  if (lane == 0) { bias[m] = acc + b[m]; S[m] = 0.f; }
}

// ---- fused GEMM: P = elu(Ab @ Bb^T + bias) [bf16], S[col] += col sums ----
// 128x128 tile, BK=32, 4 waves (2x2), 64x64/wave, global_load_lds w=16,
// double-buffered LDS, 2-phase-unrolled K loop with incremental pointers.
__global__ __launch_bounds__(256) void gemm_fused(
    const ushort* __restrict__ A1, const ushort* __restrict__ A2,
    const ushort* __restrict__ B1, const ushort* __restrict__ B2,
    const float* __restrict__ bias1, const float* __restrict__ bias2,
    ushort* __restrict__ P1, ushort* __restrict__ P2,
    float* __restrict__ S1, float* __restrict__ S2) {
  const int z = blockIdx.z;
  const ushort* __restrict__ Ab = z ? A2 : A1;
  const ushort* __restrict__ Bb = z ? B2 : B1;
  const float* __restrict__ bias = z ? bias2 : bias1;
  ushort* __restrict__ P = z ? P2 : P1;
  float* __restrict__ S = z ? S2 : S1;

  __shared__ __align__(16) ushort ldsA[2][128 * 32];
  __shared__ __align__(16) ushort ldsB[2][128 * 32];
  const int tid = threadIdx.x;
  const int lane = tid & 63;
  const int wave = tid >> 6;
  const int brow = blockIdx.x * 128, bcol = blockIdx.y * 128;
  const int wr = (wave >> 1) * 64, wc = (wave & 1) * 64;
  const int r = lane & 15, kq = lane >> 4;

  f32x4 acc[4][4] = {};

  // staging: chunk c covers (row = c>>2, 16B piece = c&3); c0 = tid, c1 = tid+256
  const int c0 = tid;
  const char* gA0 = (const char*)Ab + 2 * ((size_t)(brow + (c0 >> 2)) * KGEMM + (size_t)(c0 & 3) * 8);
  const char* gA1 = (const char*)Ab + 2 * ((size_t)(brow + 64 + (c0 >> 2)) * KGEMM + (size_t)(c0 & 3) * 8);
  const char* gB0 = (const char*)Bb + 2 * ((size_t)(bcol + (c0 >> 2)) * KGEMM + (size_t)(c0 & 3) * 8);
  const char* gB1 = (const char*)Bb + 2 * ((size_t)(bcol + 64 + (c0 >> 2)) * KGEMM + (size_t)(c0 & 3) * 8);

  auto stage = [&](ushort* bA, ushort* bB) {
    GLOAD16(gA0, (char*)bA + c0 * 16);
    GLOAD16(gA1, (char*)bA + c0 * 16 + 4096);
    GLOAD16(gB0, (char*)bB + c0 * 16);
    GLOAD16(gB1, (char*)bB + c0 * 16 + 4096);
    gA0 += 64; gA1 += 64; gB0 += 64; gB1 += 64;   // advance one K-step (32 elem)
  };

  auto compute = [&](const ushort* la, const ushort* lb) {
    const ushort* pa = la + (wr + r) * 32 + kq * 8;
    const ushort* pb = lb + (wc + r) * 32 + kq * 8;
    bf16x8 af[4], bfv[4];
#pragma unroll
    for (int mf = 0; mf < 4; ++mf)
      af[mf] = *reinterpret_cast<const bf16x8*>(pa + mf * 512);   // 16 rows * 32
#pragma unroll
    for (int nf = 0; nf < 4; ++nf)
      bfv[nf] = *reinterpret_cast<const bf16x8*>(pb + nf * 512);
#pragma unroll
    for (int mf = 0; mf < 4; ++mf)
#pragma unroll
      for (int nf = 0; nf < 4; ++nf)
        acc[mf][nf] = __builtin_amdgcn_mfma_f32_16x16x32_bf16(af[mf], bfv[nf], acc[mf][nf], 0, 0, 0);
  };

  stage(&ldsA[0][0], &ldsB[0][0]);          // k-step 0
  for (int kt = 0; kt < KGEMM / 32; kt += 2) {
    __syncthreads();
    stage(&ldsA[1][0], &ldsB[1][0]);        // k-step kt+1 (kt+1 < NK always: NK even)
    compute(&ldsA[0][0], &ldsB[0][0]);
    __syncthreads();
    if (kt + 2 < KGEMM / 32) stage(&ldsA[0][0], &ldsB[0][0]);   // k-step kt+2
    compute(&ldsA[1][0], &ldsB[1][0]);
  }

  // epilogue: bias + ELU, store P (bf16), fused per-column partial sums -> S
#pragma unroll
  for (int nf = 0; nf < 4; ++nf) {
    int col = bcol + wc + nf * 16 + r;
    float bv = bias[col];
    float cs = 0.f;
#pragma unroll
    for (int mf = 0; mf < 4; ++mf) {
#pragma unroll
      for (int j = 0; j < 4; ++j) {
        int row = brow + wr + mf * 16 + kq * 4 + j;   // C/D: col=lane&15, row=(lane>>4)*4+j
        float v = acc[mf][nf][j] + bv;
        v = v > 0.f ? v : (__expf(v) - 1.f);          // fast ELU; huge accuracy headroom
        P[(size_t)row * MDIM + col] = f2bf(v);
        cs += v;
      }
    }
    cs += __shfl_xor(cs, 16);
    cs += __shfl_xor(cs, 32);
    if (kq == 0) atomicAdd(&S[col], cs);
  }
}

// ---- logits[row] = dot(P[row,:], s); one wave per row; z merges a/b ----
__global__ __launch_bounds__(256) void gemv_logits_k(
    const ushort* __restrict__ P1, const ushort* __restrict__ P2,
    const float* __restrict__ S1, const float* __restrict__ S2,
    float* __restrict__ L) {
  int z = blockIdx.z;
  const ushort* P = z ? P2 : P1;
  const float* s = z ? S1 : S2;   // logits_a uses s2, logits_b uses s1
  float* Lz = L + (size_t)z * 8192;
  int wave = threadIdx.x >> 6, lane = threadIdx.x & 63;
  int row = blockIdx.x * 4 + wave;
  const ushort* pr = P + (size_t)row * MDIM;
  float acc = 0.f;
#pragma unroll
  for (int ch = 0; ch < 2; ++ch) {
    int base = ch * 512 + lane * 8;
    bf16x8 pv = *reinterpret_cast<const bf16x8*>(pr + base);
    const float4* sv = reinterpret_cast<const float4*>(s + base);
    float4 sa = sv[0], sb = sv[1];
    acc += bf2f((ushort)pv[0]) * sa.x + bf2f((ushort)pv[1]) * sa.y +
           bf2f((ushort)pv[2]) * sa.z + bf2f((ushort)pv[3]) * sa.w +
           bf2f((ushort)pv[4]) * sb.x + bf2f((ushort)pv[5]) * sb.y +
           bf2f((ushort)pv[6]) * sb.z + bf2f((ushort)pv[7]) * sb.w;
  }
  for (int o = 32; o; o >>= 1) acc += __shfl_down(acc, o);
  if (lane == 0) Lz[row] = acc;
}

// ---- in-place softmax over 8192 logits; blockIdx.x selects a/b ----
__global__ __launch_bounds__(256) void softmax_k(float* __restrict__ Lbase) {
  float* L = Lbase + (size_t)blockIdx.x * 8192;
  __shared__ float red[256];
  int tid = threadIdx.x;
  float v[32];
  float m = -3.4e38f;
#pragma unroll
  for (int k = 0; k < 32; ++k) { v[k] = L[tid + k * 256]; m = fmaxf(m, v[k]); }
  red[tid] = m; __syncthreads();
  for (int o = 128; o; o >>= 1) {
    if (tid < o) red[tid] = fmaxf(red[tid], red[tid + o]);
    __syncthreads();
  }
  m = red[0]; __syncthreads();
  float sum = 0.f;
#pragma unroll
  for (int k = 0; k < 32; ++k) { v[k] = expf(v[k] - m); sum += v[k]; }
  red[tid] = sum; __syncthreads();
  for (int o = 128; o; o >>= 1) {
    if (tid < o) red[tid] += red[tid + o];
    __syncthreads();
  }
  float inv = 1.f / red[0];
#pragma unroll
  for (int k = 0; k < 32; ++k) L[tid + k * 256] = v[k] * inv;
}

// ---- att[e] = sum_a w[a] * seq_bf16[a,e]; y partitions rows, atomicAdd ----
__global__ __launch_bounds__(256) void att_k(const ushort* __restrict__ s1b,
    const ushort* __restrict__ s2b, const float* __restrict__ wv,
    float* __restrict__ out) {
  int z = blockIdx.z;
  const ushort* seq = z ? s2b : s1b;
  const float* w = wv + (size_t)z * 8192;
  float* o = out + (size_t)z * EDIM;
  int e4 = threadIdx.x;                 // owns cols e4*4 .. e4*4+3
  int a0 = blockIdx.y * 64;
  float a0c = 0.f, a1c = 0.f, a2c = 0.f, a3c = 0.f;
  const ushort* p = seq + (size_t)a0 * EDIM + e4 * 4;
#pragma unroll 4
  for (int a = a0; a < a0 + 64; ++a, p += EDIM) {
    float wa = w[a];
    bf16x4 v = *reinterpret_cast<const bf16x4*>(p);
    a0c += wa * bf2f((ushort)v[0]);
    a1c += wa * bf2f((ushort)v[1]);
    a2c += wa * bf2f((ushort)v[2]);
    a3c += wa * bf2f((ushort)v[3]);
  }
  atomicAdd(&o[e4 * 4 + 0], a0c);
  atomicAdd(&o[e4 * 4 + 1], a1c);
  atomicAdd(&o[e4 * 4 + 2], a2c);
  atomicAdd(&o[e4 * 4 + 3], a3c);
}

extern "C" void kernel_launch(void* const* d_in, const int* in_sizes, int n_in,
                              void* d_out, int out_size, void* d_ws, size_t ws_size,
                              hipStream_t stream) {
  const float* seq1 = (const float*)d_in[0];
  const float* seq2 = (const float*)d_in[1];
  const float* ctx  = (const float*)d_in[2];
  const float* Wc1  = (const float*)d_in[3];
  const float* Wc2  = (const float*)d_in[4];
  const float* W1   = (const float*)d_in[5];
  const float* b1   = (const float*)d_in[6];
  const float* W2   = (const float*)d_in[7];
  const float* b2   = (const float*)d_in[8];
  float* out = (float*)d_out;
  char* ws = (char*)d_ws;

  float* bias1 = (float*)(ws + OFF_BIAS1);
  float* bias2 = (float*)(ws + OFF_BIAS2);
  float* s1    = (float*)(ws + OFF_S1);
  float* s2    = (float*)(ws + OFF_S2);
  float* loga  = (float*)(ws + OFF_LOGA);
  ushort* p1   = (ushort*)(ws + OFF_P1);
  ushort* p2   = (ushort*)(ws + OFF_P2);
  ushort* seq1b = (ushort*)(ws + OFF_SEQ1B);
  ushort* seq2b = (ushort*)(ws + OFF_SEQ2B);
  ushort* w1b   = (ushort*)(ws + OFF_W1B);
  ushort* w2b   = (ushort*)(ws + OFF_W2B);

  // zero atomic accumulation target (harness poisons once, never re-poisons)
  hipMemsetAsync(d_out, 0, sizeof(float) * 2048, stream);

  ctx_bias_k<<<dim3(256, 1, 2), 256, 0, stream>>>(Wc1, Wc2, ctx, b1, b2,
                                                  bias1, bias2, s1, s2);
  cvt_pair<<<dim3(1024, 1, 2), 256, 0, stream>>>(seq1, seq2, seq1b, seq2b,
                                                 A_ROWS * EDIM / 4);
  cvt_pair<<<dim3(128, 1, 2), 256, 0, stream>>>(W1, W2, w1b, w2b,
                                                MDIM * EDIM / 4);

  gemm_fused<<<dim3(A_ROWS / 128, MDIM / 128, 2), 256, 0, stream>>>(
      seq1b, seq2b, w1b, w2b, bias1, bias2, p1, p2, s1, s2);

  gemv_logits_k<<<dim3(2048, 1, 2), 256, 0, stream>>>(p1, p2, s1, s2, loga);

  softmax_k<<<2, 256, 0, stream>>>(loga);

  att_k<<<dim3(1, 128, 2), 256, 0, stream>>>(seq1b, seq2b, loga, out);
}

// Round 4
// 121.892 us; speedup vs baseline: 1.1261x; 1.0095x over previous
//
#include <hip/hip_runtime.h>
#include <hip/hip_bf16.h>

// OuterAttention: A=B=8192, E1=E2=C=M=1024.
// matrix_ab only used via row/col sums -> logits_a = p1 @ sum(p2), logits_b = p2 @ sum(p1).
// Round 4: GEMM K-loop rebuilt as 4-deep counted-vmcnt pipeline (T3/T4-lite):
//   4 LDS buffers, s_waitcnt vmcnt(8) (never 0 in main loop), raw s_barrier,
//   stage kt+3 after barrier, setprio(1) around MFMA cluster (T5).

#define A_ROWS 8192
#define EDIM   1024
#define MDIM   1024
#define KGEMM  1024

typedef __attribute__((ext_vector_type(8))) short bf16x8;
typedef __attribute__((ext_vector_type(4))) short bf16x4;
typedef __attribute__((ext_vector_type(4))) float f32x4;

// ---- workspace layout (bytes). Total ~68.2 MB ----
#define OFF_BIAS1   0ull
#define OFF_BIAS2   4096ull
#define OFF_S1      8192ull
#define OFF_S2      12288ull
#define OFF_LOGA    16384ull                  // 2 x 8192 floats
#define OFF_P1      81920ull                  // 8192*1024 bf16 = 16 MB
#define OFF_P2      (OFF_P1 + 16777216ull)
#define OFF_SEQ1B   (OFF_P2 + 16777216ull)    // 16 MB
#define OFF_SEQ2B   (OFF_SEQ1B + 16777216ull)
#define OFF_W1B     (OFF_SEQ2B + 16777216ull) // 2 MB
#define OFF_W2B     (OFF_W1B + 2097152ull)

__device__ __forceinline__ ushort f2bf(float x) {
  union { float f; unsigned u; } v; v.f = x;
  unsigned r = v.u + 0x7fffu + ((v.u >> 16) & 1u);   // RNE
  return (ushort)(r >> 16);
}
__device__ __forceinline__ float bf2f(ushort u) {
  union { unsigned u; float f; } v; v.u = (unsigned)u << 16; return v.f;
}

#define GLOAD16(src, dst) __builtin_amdgcn_global_load_lds( \
    (const __attribute__((address_space(1))) void*)(src),   \
    (__attribute__((address_space(3))) void*)(dst), 16, 0, 0)

#define VMWAIT8 asm volatile("s_waitcnt vmcnt(8)" ::: "memory")
#define VMWAIT4 asm volatile("s_waitcnt vmcnt(4)" ::: "memory")
#define VMWAIT0 asm volatile("s_waitcnt vmcnt(0)" ::: "memory")
#define BARRIER asm volatile("s_barrier" ::: "memory")

// ---- f32 -> bf16 convert, z picks array pair ----
__global__ __launch_bounds__(256) void cvt_pair(const float* __restrict__ in0,
    const float* __restrict__ in1, ushort* __restrict__ out0,
    ushort* __restrict__ out1, int n4) {
  const float* in = blockIdx.z ? in1 : in0;
  ushort* out = blockIdx.z ? out1 : out0;
  int stride = gridDim.x * blockDim.x;
  for (int i = blockIdx.x * blockDim.x + threadIdx.x; i < n4; i += stride) {
    float4 f = reinterpret_cast<const float4*>(in)[i];
    ushort4 o;
    o.x = f2bf(f.x); o.y = f2bf(f.y); o.z = f2bf(f.z); o.w = f2bf(f.w);
    reinterpret_cast<ushort4*>(out)[i] = o;
  }
}

// ---- bias[m] = (W_ctx @ context)[m] + b[m]; also zeros S ----
__global__ __launch_bounds__(256) void ctx_bias_k(
    const float* __restrict__ Wc1, const float* __restrict__ Wc2,
    const float* __restrict__ c, const float* __restrict__ b1,
    const float* __restrict__ b2, float* __restrict__ bias1,
    float* __restrict__ bias2, float* __restrict__ S1, float* __restrict__ S2) {
  int z = blockIdx.z;
  const float* W = z ? Wc2 : Wc1;
  const float* b = z ? b2 : b1;
  float* bias = z ? bias2 : bias1;
  float* S = z ? S2 : S1;
  int wave = threadIdx.x >> 6, lane = threadIdx.x & 63;
  int m = blockIdx.x * 4 + wave;
  const float4* wr = reinterpret_cast<const float4*>(W + (size_t)m * EDIM);
  const float4* cv = reinterpret_cast<const float4*>(c);
  float acc = 0.f;
#pragma unroll
  for (int ch = 0; ch < 4; ++ch) {
    float4 a = wr[ch * 64 + lane], d = cv[ch * 64 + lane];
    acc += a.x * d.x + a.y * d.y + a.z * d.z + a.w * d.w;
  }
  for (int o = 32; o; o >>= 1) acc += __shfl_down(acc, o);
  if (lane == 0) { bias[m] = acc + b[m]; S[m] = 0.f; }
}

// ---- fused GEMM: P = elu(Ab @ Bb^T + bias) [bf16], S[col] += col sums ----
// 128x128 tile, BK=32, 4 waves (2x2), 64x64/wave, global_load_lds w=16.
// 4-deep LDS ring + counted vmcnt: tiles kt+1,kt+2 stay in flight across
// barriers; stage(kt+3) issued after barrier (its buffer's readers all
// passed the previous barrier -> safe with ONE barrier per K-step).
__global__ __launch_bounds__(256) void gemm_fused(
    const ushort* __restrict__ A1, const ushort* __restrict__ A2,
    const ushort* __restrict__ B1, const ushort* __restrict__ B2,
    const float* __restrict__ bias1, const float* __restrict__ bias2,
    ushort* __restrict__ P1, ushort* __restrict__ P2,
    float* __restrict__ S1, float* __restrict__ S2) {
  const int z = blockIdx.z;
  const ushort* __restrict__ Ab = z ? A2 : A1;
  const ushort* __restrict__ Bb = z ? B2 : B1;
  const float* __restrict__ bias = z ? bias2 : bias1;
  ushort* __restrict__ P = z ? P2 : P1;
  float* __restrict__ S = z ? S2 : S1;

  __shared__ __align__(16) ushort ldsA[4][128 * 32];   // 4 x 8 KB
  __shared__ __align__(16) ushort ldsB[4][128 * 32];   // 4 x 8 KB
  const int tid = threadIdx.x;
  const int lane = tid & 63;
  const int wave = tid >> 6;
  const int brow = blockIdx.x * 128, bcol = blockIdx.y * 128;
  const int wr = (wave >> 1) * 64, wc = (wave & 1) * 64;
  const int r = lane & 15, kq = lane >> 4;

  f32x4 acc[4][4] = {};

  // staging: chunk c covers (row = c>>2, 16B piece = c&3); c0 = tid, +256
  const int c0 = tid;
  const char* gA0 = (const char*)Ab + 2 * ((size_t)(brow + (c0 >> 2)) * KGEMM + (size_t)(c0 & 3) * 8);
  const char* gA1 = (const char*)Ab + 2 * ((size_t)(brow + 64 + (c0 >> 2)) * KGEMM + (size_t)(c0 & 3) * 8);
  const char* gB0 = (const char*)Bb + 2 * ((size_t)(bcol + (c0 >> 2)) * KGEMM + (size_t)(c0 & 3) * 8);
  const char* gB1 = (const char*)Bb + 2 * ((size_t)(bcol + 64 + (c0 >> 2)) * KGEMM + (size_t)(c0 & 3) * 8);

  auto stage = [&](int buf) {       // 4 x 16B loads; advances one K-step (32 elem)
    char* bA = (char*)&ldsA[buf][0];
    char* bB = (char*)&ldsB[buf][0];
    GLOAD16(gA0, bA + c0 * 16);
    GLOAD16(gA1, bA + c0 * 16 + 4096);
    GLOAD16(gB0, bB + c0 * 16);
    GLOAD16(gB1, bB + c0 * 16 + 4096);
    gA0 += 64; gA1 += 64; gB0 += 64; gB1 += 64;
  };

  auto compute = [&](int buf) {
    const ushort* pa = &ldsA[buf][0] + (wr + r) * 32 + kq * 8;
    const ushort* pb = &ldsB[buf][0] + (wc + r) * 32 + kq * 8;
    bf16x8 af[4], bfv[4];
#pragma unroll
    for (int mf = 0; mf < 4; ++mf)
      af[mf] = *reinterpret_cast<const bf16x8*>(pa + mf * 512);   // 16 rows * 32
#pragma unroll
    for (int nf = 0; nf < 4; ++nf)
      bfv[nf] = *reinterpret_cast<const bf16x8*>(pb + nf * 512);
    __builtin_amdgcn_s_setprio(1);
#pragma unroll
    for (int mf = 0; mf < 4; ++mf)
#pragma unroll
      for (int nf = 0; nf < 4; ++nf)
        acc[mf][nf] = __builtin_amdgcn_mfma_f32_16x16x32_bf16(af[mf], bfv[nf], acc[mf][nf], 0, 0, 0);
    __builtin_amdgcn_s_setprio(0);
  };

  // prologue: 3 tiles in flight (12 loads/thread)
  stage(0); stage(1); stage(2);

  // main: NK=32 K-steps. Steady state keeps 8 loads (2 tiles) in flight.
  for (int kt = 0; kt < 29; ++kt) {
    VMWAIT8;          // own tile-kt loads done; barrier makes it all-waves
    BARRIER;
    stage((kt + 3) & 3);   // overwrites buf[(kt-1)&3]: readers passed prev barrier
    compute(kt & 3);
  }
  VMWAIT8; BARRIER; compute(1);   // kt=29 (tiles 30,31 still in flight)
  VMWAIT4; BARRIER; compute(2);   // kt=30
  VMWAIT0; BARRIER; compute(3);   // kt=31

  // epilogue: bias + ELU, store P (bf16), fused per-column partial sums -> S
#pragma unroll
  for (int nf = 0; nf < 4; ++nf) {
    int col = bcol + wc + nf * 16 + r;
    float bv = bias[col];
    float cs = 0.f;
#pragma unroll
    for (int mf = 0; mf < 4; ++mf) {
#pragma unroll
      for (int j = 0; j < 4; ++j) {
        int row = brow + wr + mf * 16 + kq * 4 + j;   // C/D: col=lane&15, row=(lane>>4)*4+j
        float v = acc[mf][nf][j] + bv;
        v = v > 0.f ? v : (__expf(v) - 1.f);          // fast ELU; huge accuracy headroom
        P[(size_t)row * MDIM + col] = f2bf(v);
        cs += v;
      }
    }
    cs += __shfl_xor(cs, 16);
    cs += __shfl_xor(cs, 32);
    if (kq == 0) atomicAdd(&S[col], cs);
  }
}

// ---- logits[row] = dot(P[row,:], s); one wave per row; z merges a/b ----
__global__ __launch_bounds__(256) void gemv_logits_k(
    const ushort* __restrict__ P1, const ushort* __restrict__ P2,
    const float* __restrict__ S1, const float* __restrict__ S2,
    float* __restrict__ L) {
  int z = blockIdx.z;
  const ushort* P = z ? P2 : P1;
  const float* s = z ? S1 : S2;   // logits_a uses s2, logits_b uses s1
  float* Lz = L + (size_t)z * 8192;
  int wave = threadIdx.x >> 6, lane = threadIdx.x & 63;
  int row = blockIdx.x * 4 + wave;
  const ushort* pr = P + (size_t)row * MDIM;
  float acc = 0.f;
#pragma unroll
  for (int ch = 0; ch < 2; ++ch) {
    int base = ch * 512 + lane * 8;
    bf16x8 pv = *reinterpret_cast<const bf16x8*>(pr + base);
    const float4* sv = reinterpret_cast<const float4*>(s + base);
    float4 sa = sv[0], sb = sv[1];
    acc += bf2f((ushort)pv[0]) * sa.x + bf2f((ushort)pv[1]) * sa.y +
           bf2f((ushort)pv[2]) * sa.z + bf2f((ushort)pv[3]) * sa.w +
           bf2f((ushort)pv[4]) * sb.x + bf2f((ushort)pv[5]) * sb.y +
           bf2f((ushort)pv[6]) * sb.z + bf2f((ushort)pv[7]) * sb.w;
  }
  for (int o = 32; o; o >>= 1) acc += __shfl_down(acc, o);
  if (lane == 0) Lz[row] = acc;
}

// ---- in-place softmax over 8192 logits; blockIdx.x selects a/b ----
__global__ __launch_bounds__(256) void softmax_k(float* __restrict__ Lbase) {
  float* L = Lbase + (size_t)blockIdx.x * 8192;
  __shared__ float red[256];
  int tid = threadIdx.x;
  float v[32];
  float m = -3.4e38f;
#pragma unroll
  for (int k = 0; k < 32; ++k) { v[k] = L[tid + k * 256]; m = fmaxf(m, v[k]); }
  red[tid] = m; __syncthreads();
  for (int o = 128; o; o >>= 1) {
    if (tid < o) red[tid] = fmaxf(red[tid], red[tid + o]);
    __syncthreads();
  }
  m = red[0]; __syncthreads();
  float sum = 0.f;
#pragma unroll
  for (int k = 0; k < 32; ++k) { v[k] = expf(v[k] - m); sum += v[k]; }
  red[tid] = sum; __syncthreads();
  for (int o = 128; o; o >>= 1) {
    if (tid < o) red[tid] += red[tid + o];
    __syncthreads();
  }
  float inv = 1.f / red[0];
#pragma unroll
  for (int k = 0; k < 32; ++k) L[tid + k * 256] = v[k] * inv;
}

// ---- att[e] = sum_a w[a] * seq_bf16[a,e]; y partitions rows, atomicAdd ----
__global__ __launch_bounds__(256) void att_k(const ushort* __restrict__ s1b,
    const ushort* __restrict__ s2b, const float* __restrict__ wv,
    float* __restrict__ out) {
  int z = blockIdx.z;
  const ushort* seq = z ? s2b : s1b;
  const float* w = wv + (size_t)z * 8192;
  float* o = out + (size_t)z * EDIM;
  int e4 = threadIdx.x;                 // owns cols e4*4 .. e4*4+3
  int a0 = blockIdx.y * 64;
  float a0c = 0.f, a1c = 0.f, a2c = 0.f, a3c = 0.f;
  const ushort* p = seq + (size_t)a0 * EDIM + e4 * 4;
#pragma unroll 4
  for (int a = a0; a < a0 + 64; ++a, p += EDIM) {
    float wa = w[a];
    bf16x4 v = *reinterpret_cast<const bf16x4*>(p);
    a0c += wa * bf2f((ushort)v[0]);
    a1c += wa * bf2f((ushort)v[1]);
    a2c += wa * bf2f((ushort)v[2]);
    a3c += wa * bf2f((ushort)v[3]);
  }
  atomicAdd(&o[e4 * 4 + 0], a0c);
  atomicAdd(&o[e4 * 4 + 1], a1c);
  atomicAdd(&o[e4 * 4 + 2], a2c);
  atomicAdd(&o[e4 * 4 + 3], a3c);
}

extern "C" void kernel_launch(void* const* d_in, const int* in_sizes, int n_in,
                              void* d_out, int out_size, void* d_ws, size_t ws_size,
                              hipStream_t stream) {
  const float* seq1 = (const float*)d_in[0];
  const float* seq2 = (const float*)d_in[1];
  const float* ctx  = (const float*)d_in[2];
  const float* Wc1  = (const float*)d_in[3];
  const float* Wc2  = (const float*)d_in[4];
  const float* W1   = (const float*)d_in[5];
  const float* b1   = (const float*)d_in[6];
  const float* W2   = (const float*)d_in[7];
  const float* b2   = (const float*)d_in[8];
  float* out = (float*)d_out;
  char* ws = (char*)d_ws;

  float* bias1 = (float*)(ws + OFF_BIAS1);
  float* bias2 = (float*)(ws + OFF_BIAS2);
  float* s1    = (float*)(ws + OFF_S1);
  float* s2    = (float*)(ws + OFF_S2);
  float* loga  = (float*)(ws + OFF_LOGA);
  ushort* p1   = (ushort*)(ws + OFF_P1);
  ushort* p2   = (ushort*)(ws + OFF_P2);
  ushort* seq1b = (ushort*)(ws + OFF_SEQ1B);
  ushort* seq2b = (ushort*)(ws + OFF_SEQ2B);
  ushort* w1b   = (ushort*)(ws + OFF_W1B);
  ushort* w2b   = (ushort*)(ws + OFF_W2B);

  // zero atomic accumulation target (harness poisons once, never re-poisons)
  hipMemsetAsync(d_out, 0, sizeof(float) * 2048, stream);

  ctx_bias_k<<<dim3(256, 1, 2), 256, 0, stream>>>(Wc1, Wc2, ctx, b1, b2,
                                                  bias1, bias2, s1, s2);
  cvt_pair<<<dim3(1024, 1, 2), 256, 0, stream>>>(seq1, seq2, seq1b, seq2b,
                                                 A_ROWS * EDIM / 4);
  cvt_pair<<<dim3(128, 1, 2), 256, 0, stream>>>(W1, W2, w1b, w2b,
                                                MDIM * EDIM / 4);

  gemm_fused<<<dim3(A_ROWS / 128, MDIM / 128, 2), 256, 0, stream>>>(
      seq1b, seq2b, w1b, w2b, bias1, bias2, p1, p2, s1, s2);

  gemv_logits_k<<<dim3(2048, 1, 2), 256, 0, stream>>>(p1, p2, s1, s2, loga);

  softmax_k<<<2, 256, 0, stream>>>(loga);

  att_k<<<dim3(1, 128, 2), 256, 0, stream>>>(seq1b, seq2b, loga, out);
}

// Round 5
// 103.175 us; speedup vs baseline: 1.3304x; 1.1814x over previous
//
#include <hip/hip_runtime.h>
#include <hip/hip_bf16.h>

// OuterAttention: A=B=8192, E1=E2=C=M=1024.
// matrix_ab only used via row/col sums -> logits_a = p1 @ sum(p2), logits_b = p2 @ sum(p1).
// Round 5: BK=64 (16 K-steps instead of 32; per-step cost is structural, so
// halving step count ~halves GEMM time). LDS buffer = two [128][32] k-slot
// sub-tiles (keeps the conflict-benign BK=32 bank pattern, stays linear for
// global_load_lds). softmax fused into att_k; weight-cvt merged into seq-cvt.

#define A_ROWS 8192
#define EDIM   1024
#define MDIM   1024
#define KGEMM  1024

typedef __attribute__((ext_vector_type(8))) short bf16x8;
typedef __attribute__((ext_vector_type(4))) short bf16x4;
typedef __attribute__((ext_vector_type(4))) float f32x4;

// ---- workspace layout (bytes). Total ~68.2 MB ----
#define OFF_BIAS1   0ull
#define OFF_BIAS2   4096ull
#define OFF_S1      8192ull
#define OFF_S2      12288ull
#define OFF_LOGA    16384ull                  // 2 x 8192 floats (raw logits)
#define OFF_P1      81920ull                  // 8192*1024 bf16 = 16 MB
#define OFF_P2      (OFF_P1 + 16777216ull)
#define OFF_SEQ1B   (OFF_P2 + 16777216ull)    // 16 MB
#define OFF_SEQ2B   (OFF_SEQ1B + 16777216ull)
#define OFF_W1B     (OFF_SEQ2B + 16777216ull) // 2 MB
#define OFF_W2B     (OFF_W1B + 2097152ull)

__device__ __forceinline__ ushort f2bf(float x) {
  union { float f; unsigned u; } v; v.f = x;
  unsigned r = v.u + 0x7fffu + ((v.u >> 16) & 1u);   // RNE
  return (ushort)(r >> 16);
}
__device__ __forceinline__ float bf2f(ushort u) {
  union { unsigned u; float f; } v; v.u = (unsigned)u << 16; return v.f;
}

#define GLOAD16(src, dst) __builtin_amdgcn_global_load_lds( \
    (const __attribute__((address_space(1))) void*)(src),   \
    (__attribute__((address_space(3))) void*)(dst), 16, 0, 0)

// ---- f32 -> bf16 convert; z: 0/1 = seq1/seq2, 2/3 = W1/W2 ----
__global__ __launch_bounds__(256) void cvt_all(const float* __restrict__ s1,
    const float* __restrict__ s2, const float* __restrict__ w1,
    const float* __restrict__ w2, ushort* __restrict__ s1o,
    ushort* __restrict__ s2o, ushort* __restrict__ w1o,
    ushort* __restrict__ w2o) {
  int z = blockIdx.z;
  const float* in = z == 0 ? s1 : z == 1 ? s2 : z == 2 ? w1 : w2;
  ushort* out = z == 0 ? s1o : z == 1 ? s2o : z == 2 ? w1o : w2o;
  int n4 = z < 2 ? (A_ROWS * EDIM / 4) : (MDIM * EDIM / 4);
  int stride = gridDim.x * blockDim.x;
  for (int i = blockIdx.x * blockDim.x + threadIdx.x; i < n4; i += stride) {
    float4 f = reinterpret_cast<const float4*>(in)[i];
    ushort4 o;
    o.x = f2bf(f.x); o.y = f2bf(f.y); o.z = f2bf(f.z); o.w = f2bf(f.w);
    reinterpret_cast<ushort4*>(out)[i] = o;
  }
}

// ---- bias[m] = (W_ctx @ context)[m] + b[m]; also zeros S ----
__global__ __launch_bounds__(256) void ctx_bias_k(
    const float* __restrict__ Wc1, const float* __restrict__ Wc2,
    const float* __restrict__ c, const float* __restrict__ b1,
    const float* __restrict__ b2, float* __restrict__ bias1,
    float* __restrict__ bias2, float* __restrict__ S1, float* __restrict__ S2) {
  int z = blockIdx.z;
  const float* W = z ? Wc2 : Wc1;
  const float* b = z ? b2 : b1;
  float* bias = z ? bias2 : bias1;
  float* S = z ? S2 : S1;
  int wave = threadIdx.x >> 6, lane = threadIdx.x & 63;
  int m = blockIdx.x * 4 + wave;
  const float4* wr = reinterpret_cast<const float4*>(W + (size_t)m * EDIM);
  const float4* cv = reinterpret_cast<const float4*>(c);
  float acc = 0.f;
#pragma unroll
  for (int ch = 0; ch < 4; ++ch) {
    float4 a = wr[ch * 64 + lane], d = cv[ch * 64 + lane];
    acc += a.x * d.x + a.y * d.y + a.z * d.z + a.w * d.w;
  }
  for (int o = 32; o; o >>= 1) acc += __shfl_down(acc, o);
  if (lane == 0) { bias[m] = acc + b[m]; S[m] = 0.f; }
}

// ---- fused GEMM: P = elu(Ab @ Bb^T + bias) [bf16], S[col] += col sums ----
// 128x128 tile, BK=64 (two [128][32] k-slot sub-tiles per buffer), 4 waves,
// 64x64/wave, global_load_lds w=16, double-buffered, 16 K-steps.
__global__ __launch_bounds__(256) void gemm_fused(
    const ushort* __restrict__ A1, const ushort* __restrict__ A2,
    const ushort* __restrict__ B1, const ushort* __restrict__ B2,
    const float* __restrict__ bias1, const float* __restrict__ bias2,
    ushort* __restrict__ P1, ushort* __restrict__ P2,
    float* __restrict__ S1, float* __restrict__ S2) {
  const int z = blockIdx.z;
  const ushort* __restrict__ Ab = z ? A2 : A1;
  const ushort* __restrict__ Bb = z ? B2 : B1;
  const float* __restrict__ bias = z ? bias2 : bias1;
  ushort* __restrict__ P = z ? P2 : P1;
  float* __restrict__ S = z ? S2 : S1;

  // [buf][kslot(2)][row(128)][col(32)] ushort: 16 KB per buf per operand
  __shared__ __align__(16) ushort ldsA[2][8192];
  __shared__ __align__(16) ushort ldsB[2][8192];
  const int tid = threadIdx.x;
  const int lane = tid & 63;
  const int wave = tid >> 6;
  const int brow = blockIdx.x * 128, bcol = blockIdx.y * 128;
  const int wr = (wave >> 1) * 64, wc = (wave & 1) * 64;
  const int r = lane & 15, kq = lane >> 4;

  f32x4 acc[4][4] = {};

  // Staging: LDS chunk at byte L = i*4096 + tid*16 decodes (within operand) to
  //   kslot s = L>>13, row = (L>>6)&127, piece = (L>>4)&3
  // global byte = (base_row + row)*2048 + kstep*128 + s*64 + piece*16.
  const size_t rb = (size_t)(tid >> 2) * 2048 + (size_t)(tid & 3) * 16;
  const char* gA0 = (const char*)Ab + (size_t)brow * 2048 + rb;            // s=0, rows 0-63
  const char* gA1 = gA0 + 64 * 2048;                                       // s=0, rows 64-127
  const char* gA2 = gA0 + 64;                                              // s=1, rows 0-63
  const char* gA3 = gA0 + 64 * 2048 + 64;                                  // s=1, rows 64-127
  const char* gB0 = (const char*)Bb + (size_t)bcol * 2048 + rb;
  const char* gB1 = gB0 + 64 * 2048;
  const char* gB2 = gB0 + 64;
  const char* gB3 = gB0 + 64 * 2048 + 64;

  auto stage = [&](int buf) {     // 8 x 16B loads; advances one K-step (64 elem)
    char* bA = (char*)&ldsA[buf][0] + tid * 16;
    char* bB = (char*)&ldsB[buf][0] + tid * 16;
    GLOAD16(gA0, bA);
    GLOAD16(gA1, bA + 4096);
    GLOAD16(gA2, bA + 8192);
    GLOAD16(gA3, bA + 12288);
    GLOAD16(gB0, bB);
    GLOAD16(gB1, bB + 4096);
    GLOAD16(gB2, bB + 8192);
    GLOAD16(gB3, bB + 12288);
    gA0 += 128; gA1 += 128; gA2 += 128; gA3 += 128;
    gB0 += 128; gB1 += 128; gB2 += 128; gB3 += 128;
  };

  auto compute = [&](int buf) {
    const ushort* baseA = &ldsA[buf][0] + (wr + r) * 32 + kq * 8;
    const ushort* baseB = &ldsB[buf][0] + (wc + r) * 32 + kq * 8;
#pragma unroll
    for (int ks = 0; ks < 2; ++ks) {
      bf16x8 af[4], bfv[4];
#pragma unroll
      for (int mf = 0; mf < 4; ++mf)
        af[mf] = *reinterpret_cast<const bf16x8*>(baseA + ks * 4096 + mf * 512);
#pragma unroll
      for (int nf = 0; nf < 4; ++nf)
        bfv[nf] = *reinterpret_cast<const bf16x8*>(baseB + ks * 4096 + nf * 512);
      __builtin_amdgcn_s_setprio(1);
#pragma unroll
      for (int mf = 0; mf < 4; ++mf)
#pragma unroll
        for (int nf = 0; nf < 4; ++nf)
          acc[mf][nf] = __builtin_amdgcn_mfma_f32_16x16x32_bf16(af[mf], bfv[nf], acc[mf][nf], 0, 0, 0);
      __builtin_amdgcn_s_setprio(0);
    }
  };

  stage(0);                                  // K-step 0
  for (int kt = 0; kt < 16; kt += 2) {
    __syncthreads();                         // buf0 (step kt) ready
    stage(1);                                // step kt+1 (kt+1 <= 15 always)
    compute(0);
    __syncthreads();                         // buf1 ready; buf0 readers done
    if (kt + 2 < 16) stage(0);               // step kt+2
    compute(1);
  }

  // epilogue: bias + ELU, store P (bf16), fused per-column partial sums -> S
#pragma unroll
  for (int nf = 0; nf < 4; ++nf) {
    int col = bcol + wc + nf * 16 + r;
    float bv = bias[col];
    float cs = 0.f;
#pragma unroll
    for (int mf = 0; mf < 4; ++mf) {
#pragma unroll
      for (int j = 0; j < 4; ++j) {
        int row = brow + wr + mf * 16 + kq * 4 + j;   // C/D: col=lane&15, row=(lane>>4)*4+j
        float v = acc[mf][nf][j] + bv;
        v = v > 0.f ? v : (__expf(v) - 1.f);          // fast ELU; huge accuracy headroom
        P[(size_t)row * MDIM + col] = f2bf(v);
        cs += v;
      }
    }
    cs += __shfl_xor(cs, 16);
    cs += __shfl_xor(cs, 32);
    if (kq == 0) atomicAdd(&S[col], cs);
  }
}

// ---- logits[row] = dot(P[row,:], s); one wave per row; z merges a/b ----
__global__ __launch_bounds__(256) void gemv_logits_k(
    const ushort* __restrict__ P1, const ushort* __restrict__ P2,
    const float* __restrict__ S1, const float* __restrict__ S2,
    float* __restrict__ L) {
  int z = blockIdx.z;
  const ushort* P = z ? P2 : P1;
  const float* s = z ? S1 : S2;   // logits_a uses s2, logits_b uses s1
  float* Lz = L + (size_t)z * 8192;
  int wave = threadIdx.x >> 6, lane = threadIdx.x & 63;
  int row = blockIdx.x * 4 + wave;
  const ushort* pr = P + (size_t)row * MDIM;
  float acc = 0.f;
#pragma unroll
  for (int ch = 0; ch < 2; ++ch) {
    int base = ch * 512 + lane * 8;
    bf16x8 pv = *reinterpret_cast<const bf16x8*>(pr + base);
    const float4* sv = reinterpret_cast<const float4*>(s + base);
    float4 sa = sv[0], sb = sv[1];
    acc += bf2f((ushort)pv[0]) * sa.x + bf2f((ushort)pv[1]) * sa.y +
           bf2f((ushort)pv[2]) * sa.z + bf2f((ushort)pv[3]) * sa.w +
           bf2f((ushort)pv[4]) * sb.x + bf2f((ushort)pv[5]) * sb.y +
           bf2f((ushort)pv[6]) * sb.z + bf2f((ushort)pv[7]) * sb.w;
  }
  for (int o = 32; o; o >>= 1) acc += __shfl_down(acc, o);
  if (lane == 0) Lz[row] = acc;
}

// ---- att: block-local softmax over raw logits + weighted row-sum ----
// Every block for problem z computes identical softmax stats (deterministic),
// then handles 64 rows. Removes the separate softmax dispatch.
__global__ __launch_bounds__(256) void att_sm_k(const ushort* __restrict__ s1b,
    const ushort* __restrict__ s2b, const float* __restrict__ logits,
    float* __restrict__ out) {
  int z = blockIdx.z;
  const ushort* seq = z ? s2b : s1b;
  const float* L = logits + (size_t)z * 8192;
  float* o = out + (size_t)z * EDIM;
  __shared__ float red[256];
  __shared__ float wsm[64];
  int tid = threadIdx.x;

  float lv[32];
  float m = -3.4e38f;
#pragma unroll
  for (int k = 0; k < 32; ++k) { lv[k] = L[tid + k * 256]; m = fmaxf(m, lv[k]); }
  red[tid] = m; __syncthreads();
  for (int s = 128; s; s >>= 1) {
    if (tid < s) red[tid] = fmaxf(red[tid], red[tid + s]);
    __syncthreads();
  }
  m = red[0]; __syncthreads();
  float sum = 0.f;
#pragma unroll
  for (int k = 0; k < 32; ++k) sum += __expf(lv[k] - m);
  red[tid] = sum; __syncthreads();
  for (int s = 128; s; s >>= 1) {
    if (tid < s) red[tid] += red[tid + s];
    __syncthreads();
  }
  float inv = 1.f / red[0];

  int a0 = blockIdx.y * 64;
  if (tid < 64) wsm[tid] = __expf(L[a0 + tid] - m) * inv;
  __syncthreads();

  float a0c = 0.f, a1c = 0.f, a2c = 0.f, a3c = 0.f;
  const ushort* p = seq + (size_t)a0 * EDIM + tid * 4;
#pragma unroll 4
  for (int j = 0; j < 64; ++j, p += EDIM) {
    float wa = wsm[j];
    bf16x4 v = *reinterpret_cast<const bf16x4*>(p);
    a0c += wa * bf2f((ushort)v[0]);
    a1c += wa * bf2f((ushort)v[1]);
    a2c += wa * bf2f((ushort)v[2]);
    a3c += wa * bf2f((ushort)v[3]);
  }
  atomicAdd(&o[tid * 4 + 0], a0c);
  atomicAdd(&o[tid * 4 + 1], a1c);
  atomicAdd(&o[tid * 4 + 2], a2c);
  atomicAdd(&o[tid * 4 + 3], a3c);
}

extern "C" void kernel_launch(void* const* d_in, const int* in_sizes, int n_in,
                              void* d_out, int out_size, void* d_ws, size_t ws_size,
                              hipStream_t stream) {
  const float* seq1 = (const float*)d_in[0];
  const float* seq2 = (const float*)d_in[1];
  const float* ctx  = (const float*)d_in[2];
  const float* Wc1  = (const float*)d_in[3];
  const float* Wc2  = (const float*)d_in[4];
  const float* W1   = (const float*)d_in[5];
  const float* b1   = (const float*)d_in[6];
  const float* W2   = (const float*)d_in[7];
  const float* b2   = (const float*)d_in[8];
  float* out = (float*)d_out;
  char* ws = (char*)d_ws;

  float* bias1 = (float*)(ws + OFF_BIAS1);
  float* bias2 = (float*)(ws + OFF_BIAS2);
  float* s1    = (float*)(ws + OFF_S1);
  float* s2    = (float*)(ws + OFF_S2);
  float* loga  = (float*)(ws + OFF_LOGA);
  ushort* p1   = (ushort*)(ws + OFF_P1);
  ushort* p2   = (ushort*)(ws + OFF_P2);
  ushort* seq1b = (ushort*)(ws + OFF_SEQ1B);
  ushort* seq2b = (ushort*)(ws + OFF_SEQ2B);
  ushort* w1b   = (ushort*)(ws + OFF_W1B);
  ushort* w2b   = (ushort*)(ws + OFF_W2B);

  // zero atomic accumulation target (harness poisons once, never re-poisons)
  hipMemsetAsync(d_out, 0, sizeof(float) * 2048, stream);

  ctx_bias_k<<<dim3(256, 1, 2), 256, 0, stream>>>(Wc1, Wc2, ctx, b1, b2,
                                                  bias1, bias2, s1, s2);
  cvt_all<<<dim3(512, 1, 4), 256, 0, stream>>>(seq1, seq2, W1, W2,
                                               seq1b, seq2b, w1b, w2b);

  gemm_fused<<<dim3(A_ROWS / 128, MDIM / 128, 2), 256, 0, stream>>>(
      seq1b, seq2b, w1b, w2b, bias1, bias2, p1, p2, s1, s2);

  gemv_logits_k<<<dim3(2048, 1, 2), 256, 0, stream>>>(p1, p2, s1, s2, loga);

  att_sm_k<<<dim3(1, 128, 2), 256, 0, stream>>>(seq1b, seq2b, loga, out);
}

// Round 6
// 90.148 us; speedup vs baseline: 1.5227x; 1.1445x over previous
//
#include <hip/hip_runtime.h>
#include <hip/hip_bf16.h>

// OuterAttention: A=B=8192, E1=E2=C=M=1024.
// logits_a = p1 @ sum(p2), logits_b = p2 @ sum(p1) -> no 8192^2 matrix.
// Round 6: 256^2 8-phase GEMM (T3+T4 counted vmcnt, T2 swizzle, T5 setprio),
// LDS-staged coalesced P stores, ctx_bias merged into cvt.

#define A_ROWS 8192
#define EDIM   1024
#define MDIM   1024

typedef __attribute__((ext_vector_type(8))) short bf16x8;
typedef __attribute__((ext_vector_type(4))) short bf16x4;
typedef __attribute__((ext_vector_type(4))) float f32x4;

// ---- workspace layout (bytes) ----
#define OFF_BIAS1   0ull
#define OFF_BIAS2   4096ull
#define OFF_S1      8192ull
#define OFF_S2      12288ull
#define OFF_LOGA    16384ull                  // 2 x 8192 floats (raw logits)
#define OFF_P1      81920ull                  // 8192*1024 bf16 = 16 MB
#define OFF_P2      (OFF_P1 + 16777216ull)
#define OFF_SEQ1B   (OFF_P2 + 16777216ull)    // 16 MB
#define OFF_SEQ2B   (OFF_SEQ1B + 16777216ull)
#define OFF_W1B     (OFF_SEQ2B + 16777216ull) // 2 MB
#define OFF_W2B     (OFF_W1B + 2097152ull)

__device__ __forceinline__ ushort f2bf(float x) {
  union { float f; unsigned u; } v; v.f = x;
  unsigned r = v.u + 0x7fffu + ((v.u >> 16) & 1u);   // RNE
  return (ushort)(r >> 16);
}
__device__ __forceinline__ float bf2f(ushort u) {
  union { unsigned u; float f; } v; v.u = (unsigned)u << 16; return v.f;
}

#define GLOAD16(src, dst) __builtin_amdgcn_global_load_lds( \
    (const __attribute__((address_space(1))) void*)(src),   \
    (__attribute__((address_space(3))) void*)(dst), 16, 0, 0)

// ---- prep: f32->bf16 convert (z=0..3) + ctx bias / S zero (z=4) ----
__global__ __launch_bounds__(256) void prep_k(
    const float* __restrict__ s1, const float* __restrict__ s2,
    const float* __restrict__ w1, const float* __restrict__ w2,
    ushort* __restrict__ s1o, ushort* __restrict__ s2o,
    ushort* __restrict__ w1o, ushort* __restrict__ w2o,
    const float* __restrict__ Wc1, const float* __restrict__ Wc2,
    const float* __restrict__ ctx, const float* __restrict__ b1,
    const float* __restrict__ b2, float* __restrict__ bias1,
    float* __restrict__ bias2, float* __restrict__ S1, float* __restrict__ S2) {
  int z = blockIdx.z;
  if (z < 4) {
    const float* in = z == 0 ? s1 : z == 1 ? s2 : z == 2 ? w1 : w2;
    ushort* out = z == 0 ? s1o : z == 1 ? s2o : z == 2 ? w1o : w2o;
    int n4 = z < 2 ? (A_ROWS * EDIM / 4) : (MDIM * EDIM / 4);
    int stride = gridDim.x * blockDim.x;
    for (int i = blockIdx.x * blockDim.x + threadIdx.x; i < n4; i += stride) {
      float4 f = reinterpret_cast<const float4*>(in)[i];
      ushort4 o;
      o.x = f2bf(f.x); o.y = f2bf(f.y); o.z = f2bf(f.z); o.w = f2bf(f.w);
      reinterpret_cast<ushort4*>(out)[i] = o;
    }
  } else {
    if (blockIdx.x >= 512) return;
    int zz = blockIdx.x >= 256;             // 0: problem1, 1: problem2
    int bx = blockIdx.x & 255;
    const float* W = zz ? Wc2 : Wc1;
    const float* b = zz ? b2 : b1;
    float* bias = zz ? bias2 : bias1;
    float* S = zz ? S2 : S1;
    int wave = threadIdx.x >> 6, lane = threadIdx.x & 63;
    int m = bx * 4 + wave;
    const float4* wr = reinterpret_cast<const float4*>(W + (size_t)m * EDIM);
    const float4* cv = reinterpret_cast<const float4*>(ctx);
    float acc = 0.f;
#pragma unroll
    for (int ch = 0; ch < 4; ++ch) {
      float4 a = wr[ch * 64 + lane], d = cv[ch * 64 + lane];
      acc += a.x * d.x + a.y * d.y + a.z * d.z + a.w * d.w;
    }
    for (int o = 32; o; o >>= 1) acc += __shfl_down(acc, o);
    if (lane == 0) { bias[m] = acc + b[m]; S[m] = 0.f; }
  }
}

// ---- 256x256 8-phase fused GEMM: P = elu(Ab@Bb^T + bias), S += col sums ----
// 8 waves (2M x 4N), BK=64, 128 KB LDS (A/B x 2 buf x 2 half of [128][64]),
// T2 swizzle chunk^=(row&7)<<4 (both sides), counted vmcnt(4) at p0/p4 only,
// one s_barrier per phase, setprio around each 16-MFMA cluster.
__global__ __launch_bounds__(512) void gemm8(
    const ushort* __restrict__ A1, const ushort* __restrict__ A2,
    const ushort* __restrict__ B1, const ushort* __restrict__ B2,
    const float* __restrict__ bias1, const float* __restrict__ bias2,
    ushort* __restrict__ P1, ushort* __restrict__ P2,
    float* __restrict__ S1, float* __restrict__ S2) {
  const int z = blockIdx.z;
  const ushort* __restrict__ Ab = z ? A2 : A1;
  const ushort* __restrict__ Bb = z ? B2 : B1;
  const float* __restrict__ bias = z ? bias2 : bias1;
  ushort* __restrict__ P = z ? P2 : P1;
  float* __restrict__ S = z ? S2 : S1;

  // byte map: A buf b: b*32768 (+half*16384); B: 65536 + b*32768 (+half*16384)
  __shared__ ushort lds[65536];             // 128 KB
  char* ldsb = (char*)lds;
  const char* ldsc = (const char*)lds;

  const int tid = threadIdx.x;
  const int lane = tid & 63;
  const int wave = tid >> 6;
  const int wm = wave >> 2, wn = wave & 3;
  const int r = lane & 15, kq = lane >> 4;
  const int brow = blockIdx.x * 256, bcol = blockIdx.y * 256;
  const int wrow = wm * 128, wcol = wn * 64;

  // swizzled per-lane LDS read bases (two per operand: ks=0 / ks=1)
  const int xm = (r & 7) << 4;
  const int aB0 = wm * 16384 + r * 128 + ((kq * 16) ^ xm);
  const int aB1 = wm * 16384 + r * 128 + ((64 + kq * 16) ^ xm);
  const int bRow = (wn & 1) * 64 + r;
  const int bB0 = 65536 + (wn >> 1) * 16384 + bRow * 128 + ((kq * 16) ^ xm);
  const int bB1 = 65536 + (wn >> 1) * 16384 + bRow * 128 + ((64 + kq * 16) ^ xm);

  // staging source: pre-inverse-swizzled global address (rule #21)
  const int srow = tid >> 3;                               // 0..63
  const int scb = ((tid & 7) * 16) ^ ((srow & 7) << 4);
  const char* aSrc = (const char*)Ab + (size_t)(brow + srow) * 2048 + scb;
  const char* bSrc = (const char*)Bb + (size_t)(bcol + srow) * 2048 + scb;

#define STG_A(buf, half, kt) do { \
    char* d_ = ldsb + (buf) * 32768 + (half) * 16384 + tid * 16; \
    const char* s_ = aSrc + (half) * 262144 + (kt) * 128; \
    GLOAD16(s_, d_); GLOAD16(s_ + 131072, d_ + 8192); } while (0)
#define STG_B(buf, half, kt) do { \
    char* d_ = ldsb + 65536 + (buf) * 32768 + (half) * 16384 + tid * 16; \
    const char* s_ = bSrc + (half) * 262144 + (kt) * 128; \
    GLOAD16(s_, d_); GLOAD16(s_ + 131072, d_ + 8192); } while (0)
#define RD_A0(buf, mf) (*(const bf16x8*)(ldsc + aB0 + (buf) * 32768 + (mf) * 2048))
#define RD_A1(buf, mf) (*(const bf16x8*)(ldsc + aB1 + (buf) * 32768 + (mf) * 2048))
#define RD_B0(buf, nf) (*(const bf16x8*)(ldsc + bB0 + (buf) * 32768 + (nf) * 2048))
#define RD_B1(buf, nf) (*(const bf16x8*)(ldsc + bB1 + (buf) * 32768 + (nf) * 2048))
#define VMW4 asm volatile("s_waitcnt vmcnt(4)" ::: "memory")
#define BAR __builtin_amdgcn_s_barrier()
#define MF(a, b, c) __builtin_amdgcn_mfma_f32_16x16x32_bf16((a), (b), (c), 0, 0, 0)
#define LDA(buf, mf0) do { a0k0 = RD_A0(buf, mf0); a0k1 = RD_A1(buf, mf0); \
    a1k0 = RD_A0(buf, (mf0) + 1); a1k1 = RD_A1(buf, (mf0) + 1); } while (0)
#define LDB(buf) do { \
    b0k0 = RD_B0(buf, 0); b0k1 = RD_B1(buf, 0); b1k0 = RD_B0(buf, 1); b1k1 = RD_B1(buf, 1); \
    b2k0 = RD_B0(buf, 2); b2k1 = RD_B1(buf, 2); b3k0 = RD_B0(buf, 3); b3k1 = RD_B1(buf, 3); } while (0)
#define QUAD(q) do { __builtin_amdgcn_s_setprio(1); \
    acc[q][0] = MF(a0k0, b0k0, acc[q][0]); acc[q][0] = MF(a0k1, b0k1, acc[q][0]); \
    acc[q][1] = MF(a0k0, b1k0, acc[q][1]); acc[q][1] = MF(a0k1, b1k1, acc[q][1]); \
    acc[q][2] = MF(a0k0, b2k0, acc[q][2]); acc[q][2] = MF(a0k1, b2k1, acc[q][2]); \
    acc[q][3] = MF(a0k0, b3k0, acc[q][3]); acc[q][3] = MF(a0k1, b3k1, acc[q][3]); \
    acc[(q)+1][0] = MF(a1k0, b0k0, acc[(q)+1][0]); acc[(q)+1][0] = MF(a1k1, b0k1, acc[(q)+1][0]); \
    acc[(q)+1][1] = MF(a1k0, b1k0, acc[(q)+1][1]); acc[(q)+1][1] = MF(a1k1, b1k1, acc[(q)+1][1]); \
    acc[(q)+1][2] = MF(a1k0, b2k0, acc[(q)+1][2]); acc[(q)+1][2] = MF(a1k1, b2k1, acc[(q)+1][2]); \
    acc[(q)+1][3] = MF(a1k0, b3k0, acc[(q)+1][3]); acc[(q)+1][3] = MF(a1k1, b3k1, acc[(q)+1][3]); \
    __builtin_amdgcn_s_setprio(0); } while (0)

  f32x4 acc[8][4] = {};
  bf16x8 a0k0, a0k1, a1k0, a1k1;
  bf16x8 b0k0, b0k1, b1k0, b1k1, b2k0, b2k1, b3k0, b3k1;

  // prologue: buf0 <- tile 0 (B halves then A halves), buf1.B <- tile 1
  STG_B(0, 0, 0); STG_B(0, 1, 0); STG_A(0, 0, 0); STG_A(0, 1, 0);
  STG_B(1, 0, 1); STG_B(1, 1, 1);                 // 12 loads in flight

  for (int it = 0; it < 8; ++it) {
    const int k1 = (2 * it + 1) & 15;
    const int k2 = (2 * it + 2) & 15;
    const int k3 = (2 * it + 3) & 15;
    // ---- K-tile 2it (buf0), phases 0-3 ----
    VMW4; BAR;                                 // buf0 tile fully landed (all waves)
    LDB(0); LDA(0, 0); STG_A(1, 0, k1); QUAD(0);
    BAR; LDA(0, 2); STG_A(1, 1, k1); QUAD(2);
    BAR; LDA(0, 4); STG_B(0, 0, k2); QUAD(4);
    BAR; LDA(0, 6); STG_B(0, 1, k2); QUAD(6);
    // ---- K-tile 2it+1 (buf1), phases 4-7 ----
    VMW4; BAR;                                 // buf1 tile landed
    LDB(1); LDA(1, 0); STG_A(0, 0, k2); QUAD(0);
    BAR; LDA(1, 2); STG_A(0, 1, k2); QUAD(2);
    BAR; LDA(1, 4); STG_B(1, 0, k3); QUAD(4);
    BAR; LDA(1, 6); STG_B(1, 1, k3); QUAD(6);
  }

  // ---- epilogue: drain, pack via LDS for coalesced stores ----
  asm volatile("s_waitcnt vmcnt(0)" ::: "memory");
  BAR;
  float bv[4], cs[4] = {0.f, 0.f, 0.f, 0.f};
#pragma unroll
  for (int nf = 0; nf < 4; ++nf) bv[nf] = bias[bcol + wcol + nf * 16 + r];
#pragma unroll
  for (int mf = 0; mf < 8; ++mf)
#pragma unroll
    for (int nf = 0; nf < 4; ++nf)
#pragma unroll
      for (int j = 0; j < 4; ++j) {
        float v = acc[mf][nf][j] + bv[nf];
        v = v > 0.f ? v : (__expf(v) - 1.f);
        cs[nf] += v;
        int row = wrow + mf * 16 + kq * 4 + j;       // C/D: col=lane&15, row=(lane>>4)*4+j
        lds[row * 256 + wcol + nf * 16 + r] = f2bf(v);
      }
#pragma unroll
  for (int nf = 0; nf < 4; ++nf) {
    cs[nf] += __shfl_xor(cs[nf], 16);
    cs[nf] += __shfl_xor(cs[nf], 32);
    if (kq == 0) atomicAdd(&S[bcol + wcol + nf * 16 + r], cs[nf]);
  }
  __syncthreads();
#pragma unroll
  for (int i = 0; i < 16; ++i) {
    int c = i * 512 + tid;                           // 8192 chunks of 16 B
    int row = c >> 5, coff = (c & 31) * 8;
    *(bf16x8*)(P + (size_t)(brow + row) * MDIM + bcol + coff) =
        *(const bf16x8*)(lds + row * 256 + coff);
  }
#undef STG_A
#undef STG_B
#undef RD_A0
#undef RD_A1
#undef RD_B0
#undef RD_B1
#undef VMW4
#undef BAR
#undef MF
#undef LDA
#undef LDB
#undef QUAD
}

// ---- logits[row] = dot(P[row,:], s); one wave per row; z merges a/b ----
__global__ __launch_bounds__(256) void gemv_logits_k(
    const ushort* __restrict__ P1, const ushort* __restrict__ P2,
    const float* __restrict__ S1, const float* __restrict__ S2,
    float* __restrict__ L) {
  int z = blockIdx.z;
  const ushort* P = z ? P2 : P1;
  const float* s = z ? S1 : S2;   // logits_a uses s2, logits_b uses s1
  float* Lz = L + (size_t)z * 8192;
  int wave = threadIdx.x >> 6, lane = threadIdx.x & 63;
  int row = blockIdx.x * 4 + wave;
  const ushort* pr = P + (size_t)row * MDIM;
  float acc = 0.f;
#pragma unroll
  for (int ch = 0; ch < 2; ++ch) {
    int base = ch * 512 + lane * 8;
    bf16x8 pv = *reinterpret_cast<const bf16x8*>(pr + base);
    const float4* sv = reinterpret_cast<const float4*>(s + base);
    float4 sa = sv[0], sb = sv[1];
    acc += bf2f((ushort)pv[0]) * sa.x + bf2f((ushort)pv[1]) * sa.y +
           bf2f((ushort)pv[2]) * sa.z + bf2f((ushort)pv[3]) * sa.w +
           bf2f((ushort)pv[4]) * sb.x + bf2f((ushort)pv[5]) * sb.y +
           bf2f((ushort)pv[6]) * sb.z + bf2f((ushort)pv[7]) * sb.w;
  }
  for (int o = 32; o; o >>= 1) acc += __shfl_down(acc, o);
  if (lane == 0) Lz[row] = acc;
}

// ---- att: block-local softmax over raw logits + weighted row-sum ----
__global__ __launch_bounds__(256) void att_sm_k(const ushort* __restrict__ s1b,
    const ushort* __restrict__ s2b, const float* __restrict__ logits,
    float* __restrict__ out) {
  int z = blockIdx.z;
  const ushort* seq = z ? s2b : s1b;
  const float* L = logits + (size_t)z * 8192;
  float* o = out + (size_t)z * EDIM;
  __shared__ float red[256];
  __shared__ float wsm[64];
  int tid = threadIdx.x;

  float lv[32];
  float m = -3.4e38f;
#pragma unroll
  for (int k = 0; k < 32; ++k) { lv[k] = L[tid + k * 256]; m = fmaxf(m, lv[k]); }
  red[tid] = m; __syncthreads();
  for (int s = 128; s; s >>= 1) {
    if (tid < s) red[tid] = fmaxf(red[tid], red[tid + s]);
    __syncthreads();
  }
  m = red[0]; __syncthreads();
  float sum = 0.f;
#pragma unroll
  for (int k = 0; k < 32; ++k) sum += __expf(lv[k] - m);
  red[tid] = sum; __syncthreads();
  for (int s = 128; s; s >>= 1) {
    if (tid < s) red[tid] += red[tid + s];
    __syncthreads();
  }
  float inv = 1.f / red[0];

  int a0 = blockIdx.y * 64;
  if (tid < 64) wsm[tid] = __expf(L[a0 + tid] - m) * inv;
  __syncthreads();

  float a0c = 0.f, a1c = 0.f, a2c = 0.f, a3c = 0.f;
  const ushort* p = seq + (size_t)a0 * EDIM + tid * 4;
#pragma unroll 4
  for (int j = 0; j < 64; ++j, p += EDIM) {
    float wa = wsm[j];
    bf16x4 v = *reinterpret_cast<const bf16x4*>(p);
    a0c += wa * bf2f((ushort)v[0]);
    a1c += wa * bf2f((ushort)v[1]);
    a2c += wa * bf2f((ushort)v[2]);
    a3c += wa * bf2f((ushort)v[3]);
  }
  atomicAdd(&o[tid * 4 + 0], a0c);
  atomicAdd(&o[tid * 4 + 1], a1c);
  atomicAdd(&o[tid * 4 + 2], a2c);
  atomicAdd(&o[tid * 4 + 3], a3c);
}

extern "C" void kernel_launch(void* const* d_in, const int* in_sizes, int n_in,
                              void* d_out, int out_size, void* d_ws, size_t ws_size,
                              hipStream_t stream) {
  const float* seq1 = (const float*)d_in[0];
  const float* seq2 = (const float*)d_in[1];
  const float* ctx  = (const float*)d_in[2];
  const float* Wc1  = (const float*)d_in[3];
  const float* Wc2  = (const float*)d_in[4];
  const float* W1   = (const float*)d_in[5];
  const float* b1   = (const float*)d_in[6];
  const float* W2   = (const float*)d_in[7];
  const float* b2   = (const float*)d_in[8];
  float* out = (float*)d_out;
  char* ws = (char*)d_ws;

  float* bias1 = (float*)(ws + OFF_BIAS1);
  float* bias2 = (float*)(ws + OFF_BIAS2);
  float* s1    = (float*)(ws + OFF_S1);
  float* s2    = (float*)(ws + OFF_S2);
  float* loga  = (float*)(ws + OFF_LOGA);
  ushort* p1   = (ushort*)(ws + OFF_P1);
  ushort* p2   = (ushort*)(ws + OFF_P2);
  ushort* seq1b = (ushort*)(ws + OFF_SEQ1B);
  ushort* seq2b = (ushort*)(ws + OFF_SEQ2B);
  ushort* w1b   = (ushort*)(ws + OFF_W1B);
  ushort* w2b   = (ushort*)(ws + OFF_W2B);

  // zero atomic accumulation target (harness poisons once, never re-poisons)
  hipMemsetAsync(d_out, 0, sizeof(float) * 2048, stream);

  prep_k<<<dim3(512, 1, 5), 256, 0, stream>>>(
      seq1, seq2, W1, W2, seq1b, seq2b, w1b, w2b,
      Wc1, Wc2, ctx, b1, b2, bias1, bias2, s1, s2);

  gemm8<<<dim3(A_ROWS / 256, MDIM / 256, 2), 512, 0, stream>>>(
      seq1b, seq2b, w1b, w2b, bias1, bias2, p1, p2, s1, s2);

  gemv_logits_k<<<dim3(2048, 1, 2), 256, 0, stream>>>(p1, p2, s1, s2, loga);

  att_sm_k<<<dim3(1, 128, 2), 256, 0, stream>>>(seq1b, seq2b, loga, out);
}